// Round 18
// baseline (200.147 us; speedup 1.0000x reference)
//
#include <hip/hip_runtime.h>
#include <hip/hip_bf16.h>

using bf16x8 = __attribute__((ext_vector_type(8))) __bf16;
using f32x4  = __attribute__((ext_vector_type(4))) float;

// Lessons encoded:
//  - NT hints ONLY on streaming loads (r10: nt-stores = 16x write amp on scatters).
//  - NO shared-memory float atomicAdd (r12: CAS loop, 15x).
//  - agg is L2-FILL-RATE bound: time = FETCH(88MB compulsory) / 2.2 TB/s
//    (r11/r13/r14 nulls). Do not touch agg structure.
//  - r15 bundle regressed 22us: chunk 8192 (fewer blocks = underoccupancy) and/or
//    csr scalarization. r16 = exact r14 config + ONLY the scanB->scanA fold.

// ============ fused dual-GEMM body (MFMA): [rows x 64] @ [64 x 128] bf16 ============
template<int MODE>
__device__ __forceinline__ void transform_body(
    const void* __restrict__ inv, const float* __restrict__ Wrel,
    const float* __restrict__ Wroot, const float* __restrict__ bias,
    __hip_bfloat16* __restrict__ outRel, __hip_bfloat16* __restrict__ outRoot,
    int nrows, int bid, int gsize)
{
    const int tid = threadIdx.x;
    const int w = tid >> 6, l = tid & 63;
    const int rowHalf = w & 1, colHalf = w >> 1;
    const int lr = l & 15, lg = l >> 4;

    bf16x8 Bf[4][2];
    float bval[4];
#pragma unroll
    for (int jt = 0; jt < 4; ++jt) {
        int col = colHalf * 64 + jt * 16 + lr;
        const float* wrow = (col < 64) ? (Wrel + (size_t)col * 64)
                                       : (Wroot + (size_t)(col - 64) * 64);
#pragma unroll
        for (int kb = 0; kb < 2; ++kb) {
            const float4* p = (const float4*)(wrow + kb * 32 + lg * 8);
            float4 a = p[0], b = p[1];
            bf16x8 v;
            v[0] = (__bf16)a.x; v[1] = (__bf16)a.y; v[2] = (__bf16)a.z; v[3] = (__bf16)a.w;
            v[4] = (__bf16)b.x; v[5] = (__bf16)b.y; v[6] = (__bf16)b.z; v[7] = (__bf16)b.w;
            Bf[jt][kb] = v;
        }
        bval[jt] = (col >= 64) ? bias[col - 64] : 0.f;
    }

    for (int tile = bid * 32; tile < nrows; tile += gsize * 32) {
        int arow = tile + rowHalf * 16 + lr;
        int crow = min(arow, nrows - 1);
        bf16x8 Af[2];
#pragma unroll
        for (int kb = 0; kb < 2; ++kb) {
            float xv[8];
            if (MODE == 0) {
                const float4* p = (const float4*)((const float*)inv + (size_t)crow * 64 + kb * 32 + lg * 8);
                float4 a = p[0], b = p[1];
                xv[0]=a.x; xv[1]=a.y; xv[2]=a.z; xv[3]=a.w;
                xv[4]=b.x; xv[5]=b.y; xv[6]=b.z; xv[7]=b.w;
            } else {
                const ushort4* p = (const ushort4*)((const unsigned short*)inv + (size_t)crow * 64 + kb * 32 + lg * 8);
                ushort4 a = p[0], b = p[1];
                xv[0]=__uint_as_float((unsigned)a.x<<16); xv[1]=__uint_as_float((unsigned)a.y<<16);
                xv[2]=__uint_as_float((unsigned)a.z<<16); xv[3]=__uint_as_float((unsigned)a.w<<16);
                xv[4]=__uint_as_float((unsigned)b.x<<16); xv[5]=__uint_as_float((unsigned)b.y<<16);
                xv[6]=__uint_as_float((unsigned)b.z<<16); xv[7]=__uint_as_float((unsigned)b.w<<16);
#pragma unroll
                for (int e = 0; e < 8; ++e) xv[e] = fmaxf(xv[e], 0.f);
            }
            bf16x8 v;
#pragma unroll
            for (int e = 0; e < 8; ++e) v[e] = (__bf16)xv[e];
            Af[kb] = v;
        }

        f32x4 acc[4];
#pragma unroll
        for (int jt = 0; jt < 4; ++jt) {
            acc[jt][0] = 0.f; acc[jt][1] = 0.f; acc[jt][2] = 0.f; acc[jt][3] = 0.f;
#pragma unroll
            for (int kb = 0; kb < 2; ++kb)
                acc[jt] = __builtin_amdgcn_mfma_f32_16x16x32_bf16(Af[kb], Bf[jt][kb], acc[jt], 0, 0, 0);
        }

#pragma unroll
        for (int jt = 0; jt < 4; ++jt) {
            int col = colHalf * 64 + jt * 16 + lr;
#pragma unroll
            for (int r = 0; r < 4; ++r) {
                int row = tile + rowHalf * 16 + lg * 4 + r;
                if (row < nrows) {
                    float v = acc[jt][r];
                    if (col < 64)
                        outRel[(size_t)row * 64 + col] = __float2bfloat16(v);
                    else
                        outRoot[(size_t)row * 64 + (col - 64)] = __float2bfloat16(v + bval[jt]);
                }
            }
        }
    }
}

// ============ FUSED: bucket histogram (blocks < B1) ∥ transform1 (blocks >= B1) ============
__global__ __launch_bounds__(256) void binhist_t1_k(
    const int* __restrict__ e32, const long long* __restrict__ e64,
    int* __restrict__ blockhist /*[B1][NB]*/, int E, int NB, int bshift, int chunk, int B1,
    const float* __restrict__ x, const float* __restrict__ W1rel,
    const float* __restrict__ W1root, const float* __restrict__ b1,
    __hip_bfloat16* __restrict__ outRel, __hip_bfloat16* __restrict__ outRoot, int N,
    int* __restrict__ donecnt)
{
    __shared__ int hist[512];
    __shared__ int sflag;
    if (blockIdx.x == 0 && threadIdx.x == 0) *donecnt = 0;   // reset for scanA last-block
    if ((int)blockIdx.x >= B1) {
        transform_body<0>(x, W1rel, W1root, b1, outRel, outRoot, N,
                          blockIdx.x - B1, gridDim.x - B1);
        return;
    }
    const int tid = threadIdx.x;
    if (tid < 64) {
        unsigned long long b = __ballot(e32[2 * tid + 1] != 0);
        if (tid == 0) sflag = (b == 0ULL);
    }
    for (int i = tid; i < NB; i += 256) hist[i] = 0;
    __syncthreads();
    const bool i64f = (sflag != 0);
    const int base = blockIdx.x * chunk;
    const int end  = min(base + chunk, E);
    for (int i = base + tid; i < end; i += 256) {
        int d = i64f ? (int)__builtin_nontemporal_load(e64 + (size_t)E + i)
                     : __builtin_nontemporal_load(e32 + (size_t)E + i);
        atomicAdd(&hist[d >> bshift], 1);
    }
    __syncthreads();
    int* row = blockhist + (size_t)blockIdx.x * NB;
    for (int b = tid; b < NB; b += 256) row[b] = hist[b];
}

// scanA: one block per bucket; exclusive scan over B1 (<=512) block-counts, 2/thread.
// LAST block additionally scans btot -> bucket_base (+ row_ptr[N]=E): scanB folded in.
__global__ __launch_bounds__(256) void scanA_k(
    const int* __restrict__ blockhist, int* __restrict__ bh_ex /*[NB][B1]*/,
    int* __restrict__ btot, int NB, int B1,
    int* __restrict__ donecnt, int* __restrict__ bucket_base,
    int* __restrict__ row_ptr, int N, int E)
{
    __shared__ int ts[256];
    __shared__ int amLast;
    const int t = threadIdx.x, b = blockIdx.x;
    int v0 = (2 * t     < B1) ? blockhist[(size_t)(2 * t)     * NB + b] : 0;
    int v1 = (2 * t + 1 < B1) ? blockhist[(size_t)(2 * t + 1) * NB + b] : 0;
    int s = v0 + v1;
    ts[t] = s; __syncthreads();
    for (int off = 1; off < 256; off <<= 1) {
        int y = (t >= off) ? ts[t - off] : 0;
        __syncthreads();
        ts[t] += y;
        __syncthreads();
    }
    int base = ts[t] - s;
    if (2 * t     < B1) bh_ex[(size_t)b * B1 + 2 * t]     = base;
    if (2 * t + 1 < B1) bh_ex[(size_t)b * B1 + 2 * t + 1] = base + v0;
    if (t == 255) btot[b] = ts[255];

    // ---- last-finishing block performs the bucket_base scan (was scanB) ----
    __threadfence();
    __syncthreads();
    if (t == 0) amLast = (atomicAdd(donecnt, 1) == (int)gridDim.x - 1);
    __syncthreads();
    if (!amLast) return;

    int u0 = (2 * t     < NB) ? btot[2 * t]     : 0;
    int u1 = (2 * t + 1 < NB) ? btot[2 * t + 1] : 0;
    int s2 = u0 + u1;
    __syncthreads();
    ts[t] = s2; __syncthreads();
    for (int off = 1; off < 256; off <<= 1) {
        int y = (t >= off) ? ts[t - off] : 0;
        __syncthreads();
        ts[t] += y;
        __syncthreads();
    }
    int base2 = ts[t] - s2;
    if (2 * t     < NB) bucket_base[2 * t]     = base2;
    if (2 * t + 1 < NB) bucket_base[2 * t + 1] = base2 + u0;
    if (t == 255) { bucket_base[NB] = ts[255]; row_ptr[N] = E; }
}

__global__ __launch_bounds__(256) void bin_scatter_k(
    const int* __restrict__ e32, const long long* __restrict__ e64,
    const int* __restrict__ bh_ex, const int* __restrict__ bucket_base,
    int* __restrict__ pairs, int E, int NB, int B1, int bshift, int chunk)
{
    __shared__ int ofs[512];
    __shared__ int cnt[512];
    __shared__ int sflag;
    const int tid = threadIdx.x;
    if (tid < 64) {
        unsigned long long b = __ballot(e32[2 * tid + 1] != 0);
        if (tid == 0) sflag = (b == 0ULL);
    }
    for (int b = tid; b < NB; b += 256) {
        ofs[b] = bucket_base[b] + bh_ex[(size_t)b * B1 + blockIdx.x];
        cnt[b] = 0;
    }
    __syncthreads();
    const bool i64f = (sflag != 0);
    const int base = blockIdx.x * chunk;
    const int end  = min(base + chunk, E);
    const int mask = (1 << bshift) - 1;
    for (int i = base + tid; i < end; i += 256) {
        int s, d;
        if (i64f) { s = (int)__builtin_nontemporal_load(e64 + i);
                    d = (int)__builtin_nontemporal_load(e64 + (size_t)E + i); }
        else      { s = __builtin_nontemporal_load(e32 + i);
                    d = __builtin_nontemporal_load(e32 + (size_t)E + i); }
        int b = d >> bshift;
        int r = atomicAdd(&cnt[b], 1);
        pairs[ofs[b] + r] = (s << bshift) | (d & mask);   // plain store
    }
}

__global__ __launch_bounds__(256) void buildcsr_k(
    const int* __restrict__ pairs, const int* __restrict__ bucket_base,
    int* __restrict__ row_ptr, int* __restrict__ csr, int N, int bshift)
{
    __shared__ int nh[256], sc[256], cur[256];
    const int t = threadIdx.x, b = blockIdx.x;
    const int n0 = b << bshift;
    const int nn = min(1 << bshift, N - n0);
    const int start = bucket_base[b], end = bucket_base[b + 1];
    const int mask = (1 << bshift) - 1;
    nh[t] = 0;
    __syncthreads();
    for (int i = start + t; i < end; i += 256)
        atomicAdd(&nh[pairs[i] & mask], 1);            // int LDS atomic: HW, fine
    __syncthreads();
    sc[t] = nh[t];
    __syncthreads();
    for (int off = 1; off < 256; off <<= 1) {
        int y = (t >= off) ? sc[t - off] : 0;
        __syncthreads();
        sc[t] += y;
        __syncthreads();
    }
    if (t < nn) {
        int rp = start + sc[t] - nh[t];
        row_ptr[n0 + t] = rp;
        cur[t] = rp;
    }
    __syncthreads();
    for (int i = start + t; i < end; i += 256) {
        int p = pairs[i];
        int pos = atomicAdd(&cur[p & mask], 1);
        csr[pos] = p >> bshift;                        // plain store
    }
}

// standalone transform (layer 2)
template<int MODE>
__global__ __launch_bounds__(256) void transform_mfma_k(
    const void* __restrict__ inv, const float* __restrict__ Wrel,
    const float* __restrict__ Wroot, const float* __restrict__ bias,
    __hip_bfloat16* __restrict__ outRel, __hip_bfloat16* __restrict__ outRoot,
    int nrows)
{
    transform_body<MODE>(inv, Wrel, Wroot, bias, outRel, outRoot, nrows,
                         blockIdx.x, gridDim.x);
}

// ============ CSR gather-aggregate, lane-per-channel (r14 config) ============
// Main loop 16-deep; exact tail 8/4/2/1 (wave-uniform). NT csr loads (vmcnt path).
__device__ __forceinline__ float bft(unsigned short u) {
    return __uint_as_float((unsigned)u << 16);
}

#define GATHER_BLK(W)                                                          \
    {                                                                          \
        int s[W]; float v[W];                                                  \
        _Pragma("unroll")                                                      \
        for (int j = 0; j < W; ++j) s[j] = __builtin_nontemporal_load(csr + e + j); \
        _Pragma("unroll")                                                      \
        for (int j = 0; j < W; ++j) v[j] = bft(rel[(size_t)s[j] * 64 + lane]); \
        _Pragma("unroll")                                                      \
        for (int j = 0; j < W; ++j) acc += v[j];                               \
        e += W;                                                                \
    }

template<int FUSE_FC>
__global__ __launch_bounds__(256) void agg3_k(
    const int* __restrict__ row_ptr, const int* __restrict__ csr,
    const unsigned short* __restrict__ rel, unsigned short* __restrict__ accb,
    const float* __restrict__ Wfc, const float* __restrict__ bfc,
    float* __restrict__ out, int N)
{
    const int wid  = __builtin_amdgcn_readfirstlane(threadIdx.x >> 6);
    const int lane = threadIdx.x & 63;
    const int node = blockIdx.x * 4 + wid;
    if (node >= N) return;

    const int start = row_ptr[node];
    const int end   = row_ptr[node + 1];

    float acc = bft(__builtin_nontemporal_load(accb + (size_t)node * 64 + lane));

    int e = start;
    for (; e + 16 <= end; ) GATHER_BLK(16)
    const int r = end - e;           // 0..15, wave-uniform
    if (r & 8) GATHER_BLK(8)
    if (r & 4) GATHER_BLK(4)
    if (r & 2) GATHER_BLK(2)
    if (r & 1) GATHER_BLK(1)

    if (FUSE_FC) {
        float v = fmaxf(acc, 0.f) * Wfc[lane];
        v += __int_as_float(__builtin_amdgcn_ds_swizzle(__float_as_int(v), 0x041F));
        v += __int_as_float(__builtin_amdgcn_ds_swizzle(__float_as_int(v), 0x081F));
        v += __int_as_float(__builtin_amdgcn_ds_swizzle(__float_as_int(v), 0x101F));
        v += __int_as_float(__builtin_amdgcn_ds_swizzle(__float_as_int(v), 0x201F));
        v += __int_as_float(__builtin_amdgcn_ds_swizzle(__float_as_int(v), 0x401F));
        float hi = __int_as_float(__builtin_amdgcn_readlane(__float_as_int(v), 32));
        if (lane == 0) out[node] = v + hi + bfc[0];
    } else {
        __hip_bfloat16 hb = __float2bfloat16(acc);
        accb[(size_t)node * 64 + lane] = *(unsigned short*)&hb;   // plain store (reused)
    }
}

extern "C" void kernel_launch(void* const* d_in, const int* in_sizes, int n_in,
                              void* d_out, int out_size, void* d_ws, size_t ws_size,
                              hipStream_t stream) {
    const float* x       = (const float*)d_in[0];
    const int* e32       = (const int*)d_in[1];
    const long long* e64 = (const long long*)d_in[1];
    const float* W1_rel  = (const float*)d_in[2];
    const float* W1_root = (const float*)d_in[3];
    const float* b1      = (const float*)d_in[4];
    const float* W2_rel  = (const float*)d_in[5];
    const float* W2_root = (const float*)d_in[6];
    const float* b2      = (const float*)d_in[7];
    const float* W_fc    = (const float*)d_in[8];
    const float* b_fc    = (const float*)d_in[9];
    float* out           = (float*)d_out;

    const int N = in_sizes[0] / 64;    // 100000
    const int E = in_sizes[1] / 2;     // 1600000

    const int bshift = 8;                                  // 256 nodes/bucket
    const int NB = (N + (1 << bshift) - 1) >> bshift;      // 391 (<=512)
    int chunk = 4096;                                      // r14 config: B1=391
    while ((E + chunk - 1) / chunk > 512) chunk <<= 1;
    const int B1 = (E + chunk - 1) / chunk;                // 391 (<=512)

    // workspace (~53 MB)
    char* p = (char*)d_ws;
    unsigned short* bufA   = (unsigned short*)p; p += (size_t)N * 64 * 2;  // root1 / h1
    unsigned short* bufB   = (unsigned short*)p; p += (size_t)N * 64 * 2;  // root2
    unsigned short* bufRel = (unsigned short*)p; p += (size_t)N * 64 * 2;  // rel
    int* csr         = (int*)p;  p += (size_t)E * 4;
    int* pairs       = (int*)p;  p += (size_t)E * 4;
    int* row_ptr     = (int*)p;  p += (size_t)(N + 1) * 4;
    int* blockhist   = (int*)p;  p += (size_t)B1 * NB * 4;
    int* bh_ex       = (int*)p;  p += (size_t)NB * B1 * 4;
    int* btot        = (int*)p;  p += (size_t)NB * 4;
    int* bucket_base = (int*)p;  p += (size_t)(NB + 1) * 4;
    int* donecnt     = (int*)p;

    // ---- CSR build, transform1 fused into the histogram dispatch ----
    binhist_t1_k<<<B1 + 1024, 256, 0, stream>>>(e32, e64, blockhist, E, NB, bshift, chunk, B1,
        x, W1_rel, W1_root, b1, (__hip_bfloat16*)bufRel, (__hip_bfloat16*)bufA, N, donecnt);
    scanA_k<<<NB, 256, 0, stream>>>(blockhist, bh_ex, btot, NB, B1,
        donecnt, bucket_base, row_ptr, N, E);
    bin_scatter_k<<<B1, 256, 0, stream>>>(e32, e64, bh_ex, bucket_base, pairs,
                                          E, NB, B1, bshift, chunk);
    buildcsr_k<<<NB, 256, 0, stream>>>(pairs, bucket_base, row_ptr, csr, N, bshift);

    // ---- layer 1 aggregate ----
    agg3_k<0><<<(N + 3) / 4, 256, 0, stream>>>(row_ptr, csr, bufRel, bufA,
        nullptr, nullptr, nullptr, N);

    // ---- layer 2 (+ fused FC head) ----
    transform_mfma_k<1><<<1024, 256, 0, stream>>>(bufA, W2_rel, W2_root, b2,
        (__hip_bfloat16*)bufRel, (__hip_bfloat16*)bufB, N);
    agg3_k<1><<<(N + 3) / 4, 256, 0, stream>>>(row_ptr, csr, bufRel, bufB,
        W_fc, b_fc, out, N);
}

// Round 19
// 170.830 us; speedup vs baseline: 1.1716x; 1.1716x over previous
//
#include <hip/hip_runtime.h>
#include <hip/hip_bf16.h>

using bf16x8 = __attribute__((ext_vector_type(8))) __bf16;
using f32x4  = __attribute__((ext_vector_type(4))) float;

// FINAL configuration (= round-14, best stable 171.8us; cluster 172-173 over 3 runs).
// Lessons encoded:
//  - NT hints ONLY on streaming loads (r10: nt-stores = 16x write amp on scatters).
//  - NO shared-memory float atomicAdd (r12: CAS loop, 15x slowdown).
//  - agg is L2-FILL-RATE bound: time = FETCH(88MB compulsory: 8 XCD x unique src
//    lines) / 2.2 TB/s. Four structural nulls confirm (r11/r13/r14).
//  - chunk 4096 / B1=391: more blocks beats less write-amp (r15 regression).
//  - separate scanB dispatch beats last-block-done fold: device-scope
//    __threadfence per block is ~28us on 8-XCD CDNA4 (r15/r18 regressions).

// ============ fused dual-GEMM body (MFMA): [rows x 64] @ [64 x 128] bf16 ============
template<int MODE>
__device__ __forceinline__ void transform_body(
    const void* __restrict__ inv, const float* __restrict__ Wrel,
    const float* __restrict__ Wroot, const float* __restrict__ bias,
    __hip_bfloat16* __restrict__ outRel, __hip_bfloat16* __restrict__ outRoot,
    int nrows, int bid, int gsize)
{
    const int tid = threadIdx.x;
    const int w = tid >> 6, l = tid & 63;
    const int rowHalf = w & 1, colHalf = w >> 1;
    const int lr = l & 15, lg = l >> 4;

    bf16x8 Bf[4][2];
    float bval[4];
#pragma unroll
    for (int jt = 0; jt < 4; ++jt) {
        int col = colHalf * 64 + jt * 16 + lr;
        const float* wrow = (col < 64) ? (Wrel + (size_t)col * 64)
                                       : (Wroot + (size_t)(col - 64) * 64);
#pragma unroll
        for (int kb = 0; kb < 2; ++kb) {
            const float4* p = (const float4*)(wrow + kb * 32 + lg * 8);
            float4 a = p[0], b = p[1];
            bf16x8 v;
            v[0] = (__bf16)a.x; v[1] = (__bf16)a.y; v[2] = (__bf16)a.z; v[3] = (__bf16)a.w;
            v[4] = (__bf16)b.x; v[5] = (__bf16)b.y; v[6] = (__bf16)b.z; v[7] = (__bf16)b.w;
            Bf[jt][kb] = v;
        }
        bval[jt] = (col >= 64) ? bias[col - 64] : 0.f;
    }

    for (int tile = bid * 32; tile < nrows; tile += gsize * 32) {
        int arow = tile + rowHalf * 16 + lr;
        int crow = min(arow, nrows - 1);
        bf16x8 Af[2];
#pragma unroll
        for (int kb = 0; kb < 2; ++kb) {
            float xv[8];
            if (MODE == 0) {
                const float4* p = (const float4*)((const float*)inv + (size_t)crow * 64 + kb * 32 + lg * 8);
                float4 a = p[0], b = p[1];
                xv[0]=a.x; xv[1]=a.y; xv[2]=a.z; xv[3]=a.w;
                xv[4]=b.x; xv[5]=b.y; xv[6]=b.z; xv[7]=b.w;
            } else {
                const ushort4* p = (const ushort4*)((const unsigned short*)inv + (size_t)crow * 64 + kb * 32 + lg * 8);
                ushort4 a = p[0], b = p[1];
                xv[0]=__uint_as_float((unsigned)a.x<<16); xv[1]=__uint_as_float((unsigned)a.y<<16);
                xv[2]=__uint_as_float((unsigned)a.z<<16); xv[3]=__uint_as_float((unsigned)a.w<<16);
                xv[4]=__uint_as_float((unsigned)b.x<<16); xv[5]=__uint_as_float((unsigned)b.y<<16);
                xv[6]=__uint_as_float((unsigned)b.z<<16); xv[7]=__uint_as_float((unsigned)b.w<<16);
#pragma unroll
                for (int e = 0; e < 8; ++e) xv[e] = fmaxf(xv[e], 0.f);
            }
            bf16x8 v;
#pragma unroll
            for (int e = 0; e < 8; ++e) v[e] = (__bf16)xv[e];
            Af[kb] = v;
        }

        f32x4 acc[4];
#pragma unroll
        for (int jt = 0; jt < 4; ++jt) {
            acc[jt][0] = 0.f; acc[jt][1] = 0.f; acc[jt][2] = 0.f; acc[jt][3] = 0.f;
#pragma unroll
            for (int kb = 0; kb < 2; ++kb)
                acc[jt] = __builtin_amdgcn_mfma_f32_16x16x32_bf16(Af[kb], Bf[jt][kb], acc[jt], 0, 0, 0);
        }

#pragma unroll
        for (int jt = 0; jt < 4; ++jt) {
            int col = colHalf * 64 + jt * 16 + lr;
#pragma unroll
            for (int r = 0; r < 4; ++r) {
                int row = tile + rowHalf * 16 + lg * 4 + r;
                if (row < nrows) {
                    float v = acc[jt][r];
                    if (col < 64)
                        outRel[(size_t)row * 64 + col] = __float2bfloat16(v);
                    else
                        outRoot[(size_t)row * 64 + (col - 64)] = __float2bfloat16(v + bval[jt]);
                }
            }
        }
    }
}

// ============ FUSED: bucket histogram (blocks < B1) ∥ transform1 (blocks >= B1) ============
__global__ __launch_bounds__(256) void binhist_t1_k(
    const int* __restrict__ e32, const long long* __restrict__ e64,
    int* __restrict__ blockhist /*[B1][NB]*/, int E, int NB, int bshift, int chunk, int B1,
    const float* __restrict__ x, const float* __restrict__ W1rel,
    const float* __restrict__ W1root, const float* __restrict__ b1,
    __hip_bfloat16* __restrict__ outRel, __hip_bfloat16* __restrict__ outRoot, int N)
{
    __shared__ int hist[512];
    __shared__ int sflag;
    if ((int)blockIdx.x >= B1) {
        transform_body<0>(x, W1rel, W1root, b1, outRel, outRoot, N,
                          blockIdx.x - B1, gridDim.x - B1);
        return;
    }
    const int tid = threadIdx.x;
    if (tid < 64) {
        unsigned long long b = __ballot(e32[2 * tid + 1] != 0);
        if (tid == 0) sflag = (b == 0ULL);
    }
    for (int i = tid; i < NB; i += 256) hist[i] = 0;
    __syncthreads();
    const bool i64f = (sflag != 0);
    const int base = blockIdx.x * chunk;
    const int end  = min(base + chunk, E);
    for (int i = base + tid; i < end; i += 256) {
        int d = i64f ? (int)__builtin_nontemporal_load(e64 + (size_t)E + i)
                     : __builtin_nontemporal_load(e32 + (size_t)E + i);
        atomicAdd(&hist[d >> bshift], 1);
    }
    __syncthreads();
    int* row = blockhist + (size_t)blockIdx.x * NB;
    for (int b = tid; b < NB; b += 256) row[b] = hist[b];
}

// scanA: one block per bucket; exclusive scan over B1 (<=512) block-counts, 2/thread.
__global__ __launch_bounds__(256) void scanA_k(
    const int* __restrict__ blockhist, int* __restrict__ bh_ex /*[NB][B1]*/,
    int* __restrict__ btot, int NB, int B1)
{
    __shared__ int ts[256];
    const int t = threadIdx.x, b = blockIdx.x;
    int v0 = (2 * t     < B1) ? blockhist[(size_t)(2 * t)     * NB + b] : 0;
    int v1 = (2 * t + 1 < B1) ? blockhist[(size_t)(2 * t + 1) * NB + b] : 0;
    int s = v0 + v1;
    ts[t] = s; __syncthreads();
    for (int off = 1; off < 256; off <<= 1) {
        int y = (t >= off) ? ts[t - off] : 0;
        __syncthreads();
        ts[t] += y;
        __syncthreads();
    }
    int base = ts[t] - s;   // exclusive base for this thread's pair
    if (2 * t     < B1) bh_ex[(size_t)b * B1 + 2 * t]     = base;
    if (2 * t + 1 < B1) bh_ex[(size_t)b * B1 + 2 * t + 1] = base + v0;
    if (t == 255) btot[b] = ts[255];
}

__global__ __launch_bounds__(256) void scanB_k(
    const int* __restrict__ btot, int* __restrict__ bucket_base,
    int* __restrict__ row_ptr, int NB, int N)
{
    __shared__ int ts[256];
    const int t = threadIdx.x;
    int v[4], s = 0;
#pragma unroll
    for (int j = 0; j < 4; ++j) { int i = t * 4 + j; v[j] = (i < NB) ? btot[i] : 0; s += v[j]; }
    ts[t] = s; __syncthreads();
    for (int off = 1; off < 256; off <<= 1) {
        int x = (t >= off) ? ts[t - off] : 0;
        __syncthreads();
        ts[t] += x;
        __syncthreads();
    }
    int base = ts[t] - s;
#pragma unroll
    for (int j = 0; j < 4; ++j) {
        int i = t * 4 + j;
        if (i < NB) { bucket_base[i] = base; base += v[j]; }
    }
    if (t == 255) { bucket_base[NB] = ts[255]; row_ptr[N] = ts[255]; }
}

__global__ __launch_bounds__(256) void bin_scatter_k(
    const int* __restrict__ e32, const long long* __restrict__ e64,
    const int* __restrict__ bh_ex, const int* __restrict__ bucket_base,
    int* __restrict__ pairs, int E, int NB, int B1, int bshift, int chunk)
{
    __shared__ int ofs[512];
    __shared__ int cnt[512];
    __shared__ int sflag;
    const int tid = threadIdx.x;
    if (tid < 64) {
        unsigned long long b = __ballot(e32[2 * tid + 1] != 0);
        if (tid == 0) sflag = (b == 0ULL);
    }
    for (int b = tid; b < NB; b += 256) {
        ofs[b] = bucket_base[b] + bh_ex[(size_t)b * B1 + blockIdx.x];
        cnt[b] = 0;
    }
    __syncthreads();
    const bool i64f = (sflag != 0);
    const int base = blockIdx.x * chunk;
    const int end  = min(base + chunk, E);
    const int mask = (1 << bshift) - 1;
    for (int i = base + tid; i < end; i += 256) {
        int s, d;
        if (i64f) { s = (int)__builtin_nontemporal_load(e64 + i);
                    d = (int)__builtin_nontemporal_load(e64 + (size_t)E + i); }
        else      { s = __builtin_nontemporal_load(e32 + i);
                    d = __builtin_nontemporal_load(e32 + (size_t)E + i); }
        int b = d >> bshift;
        int r = atomicAdd(&cnt[b], 1);
        pairs[ofs[b] + r] = (s << bshift) | (d & mask);   // plain store
    }
}

__global__ __launch_bounds__(256) void buildcsr_k(
    const int* __restrict__ pairs, const int* __restrict__ bucket_base,
    int* __restrict__ row_ptr, int* __restrict__ csr, int N, int bshift)
{
    __shared__ int nh[256], sc[256], cur[256];
    const int t = threadIdx.x, b = blockIdx.x;
    const int n0 = b << bshift;
    const int nn = min(1 << bshift, N - n0);
    const int start = bucket_base[b], end = bucket_base[b + 1];
    const int mask = (1 << bshift) - 1;
    nh[t] = 0;
    __syncthreads();
    for (int i = start + t; i < end; i += 256)
        atomicAdd(&nh[pairs[i] & mask], 1);            // int LDS atomic: HW, fine
    __syncthreads();
    sc[t] = nh[t];
    __syncthreads();
    for (int off = 1; off < 256; off <<= 1) {
        int y = (t >= off) ? sc[t - off] : 0;
        __syncthreads();
        sc[t] += y;
        __syncthreads();
    }
    if (t < nn) {
        int rp = start + sc[t] - nh[t];
        row_ptr[n0 + t] = rp;
        cur[t] = rp;
    }
    __syncthreads();
    for (int i = start + t; i < end; i += 256) {
        int p = pairs[i];
        int pos = atomicAdd(&cur[p & mask], 1);
        csr[pos] = p >> bshift;                        // plain store
    }
}

// standalone transform (layer 2)
template<int MODE>
__global__ __launch_bounds__(256) void transform_mfma_k(
    const void* __restrict__ inv, const float* __restrict__ Wrel,
    const float* __restrict__ Wroot, const float* __restrict__ bias,
    __hip_bfloat16* __restrict__ outRel, __hip_bfloat16* __restrict__ outRoot,
    int nrows)
{
    transform_body<MODE>(inv, Wrel, Wroot, bias, outRel, outRoot, nrows,
                         blockIdx.x, gridDim.x);
}

// ============ CSR gather-aggregate, lane-per-channel ============
// Main loop 16-deep; exact tail 8/4/2/1 (wave-uniform). NT csr loads (vmcnt path).
__device__ __forceinline__ float bft(unsigned short u) {
    return __uint_as_float((unsigned)u << 16);
}

#define GATHER_BLK(W)                                                          \
    {                                                                          \
        int s[W]; float v[W];                                                  \
        _Pragma("unroll")                                                      \
        for (int j = 0; j < W; ++j) s[j] = __builtin_nontemporal_load(csr + e + j); \
        _Pragma("unroll")                                                      \
        for (int j = 0; j < W; ++j) v[j] = bft(rel[(size_t)s[j] * 64 + lane]); \
        _Pragma("unroll")                                                      \
        for (int j = 0; j < W; ++j) acc += v[j];                               \
        e += W;                                                                \
    }

template<int FUSE_FC>
__global__ __launch_bounds__(256) void agg3_k(
    const int* __restrict__ row_ptr, const int* __restrict__ csr,
    const unsigned short* __restrict__ rel, unsigned short* __restrict__ accb,
    const float* __restrict__ Wfc, const float* __restrict__ bfc,
    float* __restrict__ out, int N)
{
    const int wid  = __builtin_amdgcn_readfirstlane(threadIdx.x >> 6);
    const int lane = threadIdx.x & 63;
    const int node = blockIdx.x * 4 + wid;
    if (node >= N) return;

    const int start = row_ptr[node];
    const int end   = row_ptr[node + 1];

    float acc = bft(__builtin_nontemporal_load(accb + (size_t)node * 64 + lane));

    int e = start;
    for (; e + 16 <= end; ) GATHER_BLK(16)
    const int r = end - e;           // 0..15, wave-uniform
    if (r & 8) GATHER_BLK(8)
    if (r & 4) GATHER_BLK(4)
    if (r & 2) GATHER_BLK(2)
    if (r & 1) GATHER_BLK(1)

    if (FUSE_FC) {
        float v = fmaxf(acc, 0.f) * Wfc[lane];
        v += __int_as_float(__builtin_amdgcn_ds_swizzle(__float_as_int(v), 0x041F));
        v += __int_as_float(__builtin_amdgcn_ds_swizzle(__float_as_int(v), 0x081F));
        v += __int_as_float(__builtin_amdgcn_ds_swizzle(__float_as_int(v), 0x101F));
        v += __int_as_float(__builtin_amdgcn_ds_swizzle(__float_as_int(v), 0x201F));
        v += __int_as_float(__builtin_amdgcn_ds_swizzle(__float_as_int(v), 0x401F));
        float hi = __int_as_float(__builtin_amdgcn_readlane(__float_as_int(v), 32));
        if (lane == 0) out[node] = v + hi + bfc[0];
    } else {
        __hip_bfloat16 hb = __float2bfloat16(acc);
        accb[(size_t)node * 64 + lane] = *(unsigned short*)&hb;   // plain store (reused)
    }
}

extern "C" void kernel_launch(void* const* d_in, const int* in_sizes, int n_in,
                              void* d_out, int out_size, void* d_ws, size_t ws_size,
                              hipStream_t stream) {
    const float* x       = (const float*)d_in[0];
    const int* e32       = (const int*)d_in[1];
    const long long* e64 = (const long long*)d_in[1];
    const float* W1_rel  = (const float*)d_in[2];
    const float* W1_root = (const float*)d_in[3];
    const float* b1      = (const float*)d_in[4];
    const float* W2_rel  = (const float*)d_in[5];
    const float* W2_root = (const float*)d_in[6];
    const float* b2      = (const float*)d_in[7];
    const float* W_fc    = (const float*)d_in[8];
    const float* b_fc    = (const float*)d_in[9];
    float* out           = (float*)d_out;

    const int N = in_sizes[0] / 64;    // 100000
    const int E = in_sizes[1] / 2;     // 1600000

    const int bshift = 8;                                  // 256 nodes/bucket
    const int NB = (N + (1 << bshift) - 1) >> bshift;      // 391 (<=512)
    int chunk = 4096;
    while ((E + chunk - 1) / chunk > 512) chunk <<= 1;
    const int B1 = (E + chunk - 1) / chunk;                // 391 (<=512)

    // workspace (~53 MB)
    char* p = (char*)d_ws;
    unsigned short* bufA   = (unsigned short*)p; p += (size_t)N * 64 * 2;  // root1 / h1
    unsigned short* bufB   = (unsigned short*)p; p += (size_t)N * 64 * 2;  // root2
    unsigned short* bufRel = (unsigned short*)p; p += (size_t)N * 64 * 2;  // rel
    int* csr         = (int*)p;  p += (size_t)E * 4;
    int* pairs       = (int*)p;  p += (size_t)E * 4;
    int* row_ptr     = (int*)p;  p += (size_t)(N + 1) * 4;
    int* blockhist   = (int*)p;  p += (size_t)B1 * NB * 4;
    int* bh_ex       = (int*)p;  p += (size_t)NB * B1 * 4;
    int* btot        = (int*)p;  p += (size_t)NB * 4;
    int* bucket_base = (int*)p;

    // ---- CSR build, with transform1 fused into the histogram dispatch ----
    binhist_t1_k<<<B1 + 1024, 256, 0, stream>>>(e32, e64, blockhist, E, NB, bshift, chunk, B1,
        x, W1_rel, W1_root, b1, (__hip_bfloat16*)bufRel, (__hip_bfloat16*)bufA, N);
    scanA_k<<<NB, 256, 0, stream>>>(blockhist, bh_ex, btot, NB, B1);
    scanB_k<<<1, 256, 0, stream>>>(btot, bucket_base, row_ptr, NB, N);
    bin_scatter_k<<<B1, 256, 0, stream>>>(e32, e64, bh_ex, bucket_base, pairs,
                                          E, NB, B1, bshift, chunk);
    buildcsr_k<<<NB, 256, 0, stream>>>(pairs, bucket_base, row_ptr, csr, N, bshift);

    // ---- layer 1 aggregate ----
    agg3_k<0><<<(N + 3) / 4, 256, 0, stream>>>(row_ptr, csr, bufRel, bufA,
        nullptr, nullptr, nullptr, N);

    // ---- layer 2 (+ fused FC head) ----
    transform_mfma_k<1><<<1024, 256, 0, stream>>>(bufA, W2_rel, W2_root, b2,
        (__hip_bfloat16*)bufRel, (__hip_bfloat16*)bufB, N);
    agg3_k<1><<<(N + 3) / 4, 256, 0, stream>>>(row_ptr, csr, bufRel, bufB,
        W_fc, b_fc, out, N);
}